// Round 5
// baseline (4154.501 us; speedup 1.0000x reference)
//
#include <hip/hip_runtime.h>
#include <hip/hip_bf16.h>

using bf16 = __hip_bfloat16;

constexpr int NB = 8, NS = 512, ND = 768, NH = 12, NE = 8, NF = 3072, NT = 4096;
constexpr int HG = 4;            // heads per attention group
constexpr int NG = NH / HG;      // 3 groups
constexpr int GW = HG * 64;      // 256: qkv group width
constexpr int FQ = 768;          // F columns per MoE pass
constexpr int NP = NF / FQ;      // 4 passes

__device__ __forceinline__ float toF(float v) { return v; }
__device__ __forceinline__ float toF(bf16 v) { return __bfloat162float(v); }

// ---------------- LayerNorm (fp32 in) -> TOUT out ----------------
template <typename TOUT>
__launch_bounds__(256)
__global__ void ln_kernel(const float* __restrict__ x, const float* __restrict__ g,
                          const float* __restrict__ b, TOUT* __restrict__ out) {
    const int t = blockIdx.x;
    const int tid = threadIdx.x;
    const float* xr = x + (size_t)t * ND;
    float v0 = xr[tid], v1 = xr[tid + 256], v2 = xr[tid + 512];
    float s = v0 + v1 + v2;
    float ss = v0 * v0 + v1 * v1 + v2 * v2;
#pragma unroll
    for (int off = 32; off >= 1; off >>= 1) {
        s += __shfl_xor(s, off);
        ss += __shfl_xor(ss, off);
    }
    __shared__ float rs[4], rss[4];
    const int wv = tid >> 6, ln = tid & 63;
    if (ln == 0) { rs[wv] = s; rss[wv] = ss; }
    __syncthreads();
    float S = rs[0] + rs[1] + rs[2] + rs[3];
    float SS = rss[0] + rss[1] + rss[2] + rss[3];
    float mu = S * (1.0f / ND);
    float var = SS * (1.0f / ND) - mu * mu;
    float r = rsqrtf(fmaxf(var, 0.f) + 1e-5f);
    TOUT* orow = out + (size_t)t * ND;
    float o0 = (v0 - mu) * r * g[tid]       + b[tid];
    float o1 = (v1 - mu) * r * g[tid + 256] + b[tid + 256];
    float o2 = (v2 - mu) * r * g[tid + 512] + b[tid + 512];
    if constexpr (sizeof(TOUT) == 2) {
        orow[tid] = __float2bfloat16(o0);
        orow[tid + 256] = __float2bfloat16(o1);
        orow[tid + 512] = __float2bfloat16(o2);
    } else {
        orow[tid] = o0; orow[tid + 256] = o1; orow[tid + 512] = o2;
    }
}

// ---- fp32 GEMM: 64x64 tile, BK=16. RES_MODE: 0 store, 1 store Res+acc, 2 C += acc ----
template <int RES_MODE>
__launch_bounds__(256)
__global__ void gemm_kernel(const float* __restrict__ A, int lda, const float* __restrict__ Bw,
                            int ldb, int bcol0, const float* __restrict__ Res,
                            float* __restrict__ C, int ldc, int Kd) {
    __shared__ float As[16][65];
    __shared__ float Bs[16][64];
    const int m0 = blockIdx.x * 64, n0 = blockIdx.y * 64;
    const int tid = threadIdx.x, tx = tid & 15, ty = tid >> 4;
    float acc[4][4] = {};
    for (int k0 = 0; k0 < Kd; k0 += 16) {
#pragma unroll
        for (int i = 0; i < 4; i++) {
            int idx = tid + 256 * i;
            int r = idx >> 4, kk = idx & 15;
            As[kk][r] = A[(size_t)(m0 + r) * lda + k0 + kk];
        }
#pragma unroll
        for (int i = 0; i < 4; i++) {
            int idx = tid + 256 * i;
            int kk = idx >> 6, c = idx & 63;
            Bs[kk][c] = Bw[(size_t)(k0 + kk) * ldb + bcol0 + n0 + c];
        }
        __syncthreads();
#pragma unroll
        for (int kk = 0; kk < 16; kk++) {
            float a[4], bb[4];
#pragma unroll
            for (int i = 0; i < 4; i++) a[i] = As[kk][ty + 16 * i];
#pragma unroll
            for (int j = 0; j < 4; j++) bb[j] = Bs[kk][tx + 16 * j];
#pragma unroll
            for (int i = 0; i < 4; i++)
#pragma unroll
                for (int j = 0; j < 4; j++) acc[i][j] += a[i] * bb[j];
        }
        __syncthreads();
    }
#pragma unroll
    for (int i = 0; i < 4; i++) {
        int r = m0 + ty + 16 * i;
#pragma unroll
        for (int j = 0; j < 4; j++) {
            int c = n0 + tx + 16 * j;
            size_t ci = (size_t)r * ldc + c;
            if (RES_MODE == 0) C[ci] = acc[i][j];
            else if (RES_MODE == 1) C[ci] = Res[ci] + acc[i][j];
            else C[ci] += acc[i][j];
        }
    }
}

// ------- fp32 flash attention (one head of a group); q/k/v/o [NT, GW] -------
__launch_bounds__(256)
__global__ void attn_kernel(const float* __restrict__ q, const float* __restrict__ k,
                            const float* __restrict__ v, float* __restrict__ o) {
    __shared__ float qs[64][65];
    __shared__ float kp[64][65]; // K tile, reused as P tile
    __shared__ float vs[64][65];
    const int qt = blockIdx.x, hl = blockIdx.y, b = blockIdx.z;
    const int tid = threadIdx.x, tx = tid & 15, ty = tid >> 4;
    const int hc = hl * 64;
#pragma unroll
    for (int i = 0; i < 16; i++) {
        int idx = tid + 256 * i;
        int r = idx >> 6, c = idx & 63;
        qs[r][c] = q[((size_t)b * NS + qt * 64 + r) * GW + hc + c];
    }
    float oa[4][4] = {};
    float mi[4], li[4], al[4];
#pragma unroll
    for (int i = 0; i < 4; i++) { mi[i] = -1.0e30f; li[i] = 0.f; }
    for (int kt = 0; kt < NS / 64; kt++) {
        __syncthreads();
#pragma unroll
        for (int i = 0; i < 16; i++) {
            int idx = tid + 256 * i;
            int r = idx >> 6, c = idx & 63;
            size_t ga = ((size_t)b * NS + kt * 64 + r) * GW + hc + c;
            kp[r][c] = k[ga];
            vs[r][c] = v[ga];
        }
        __syncthreads();
        float s[4][4] = {};
#pragma unroll
        for (int d = 0; d < 64; d++) {
            float a[4], bb[4];
#pragma unroll
            for (int i = 0; i < 4; i++) a[i] = qs[ty + 16 * i][d];
#pragma unroll
            for (int j = 0; j < 4; j++) bb[j] = kp[tx + 16 * j][d];
#pragma unroll
            for (int i = 0; i < 4; i++)
#pragma unroll
                for (int j = 0; j < 4; j++) s[i][j] += a[i] * bb[j];
        }
#pragma unroll
        for (int i = 0; i < 4; i++) {
#pragma unroll
            for (int j = 0; j < 4; j++) s[i][j] *= 0.125f; // 1/sqrt(DH=64)
            float mt = fmaxf(fmaxf(s[i][0], s[i][1]), fmaxf(s[i][2], s[i][3]));
#pragma unroll
            for (int off = 1; off < 16; off <<= 1) mt = fmaxf(mt, __shfl_xor(mt, off));
            float mn = fmaxf(mi[i], mt);
            al[i] = __expf(mi[i] - mn);
            mi[i] = mn;
            float rsum = 0.f;
#pragma unroll
            for (int j = 0; j < 4; j++) {
                s[i][j] = __expf(s[i][j] - mn);
                rsum += s[i][j];
            }
#pragma unroll
            for (int off = 1; off < 16; off <<= 1) rsum += __shfl_xor(rsum, off);
            li[i] = li[i] * al[i] + rsum;
        }
        __syncthreads(); // reads of kp-as-K done
#pragma unroll
        for (int i = 0; i < 4; i++)
#pragma unroll
            for (int j = 0; j < 4; j++) {
                kp[ty + 16 * i][tx + 16 * j] = s[i][j];
                oa[i][j] *= al[i];
            }
        __syncthreads(); // P visible
#pragma unroll
        for (int d = 0; d < 64; d++) {
            float a[4], bb[4];
#pragma unroll
            for (int i = 0; i < 4; i++) a[i] = kp[ty + 16 * i][d];
#pragma unroll
            for (int j = 0; j < 4; j++) bb[j] = vs[d][tx + 16 * j];
#pragma unroll
            for (int i = 0; i < 4; i++)
#pragma unroll
                for (int j = 0; j < 4; j++) oa[i][j] += a[i] * bb[j];
        }
    }
#pragma unroll
    for (int i = 0; i < 4; i++) {
        float inv = 1.0f / li[i];
#pragma unroll
        for (int j = 0; j < 4; j++)
            o[((size_t)b * NS + qt * 64 + ty + 16 * i) * GW + hc + tx + 16 * j] = oa[i][j] * inv;
    }
}

// ------- Routing: inline fp32 LN2(x1) -> logits -> top-2. One wave per token. -------
__launch_bounds__(256)
__global__ void route_kernel(const float* __restrict__ x1, const float* __restrict__ lg,
                             const float* __restrict__ lb, const float* __restrict__ gw,
                             const float* __restrict__ gb, const float* __restrict__ be,
                             int* __restrict__ cnt, int* __restrict__ list,
                             float* __restrict__ gates) {
    const int lane = threadIdx.x & 63;
    const int t = blockIdx.x * 4 + (threadIdx.x >> 6);
    if (t >= NT) return;
    const float* xr = x1 + (size_t)t * ND;
    float xv[12];
    float s = 0.f, ss = 0.f;
#pragma unroll
    for (int i = 0; i < 12; i++) {
        xv[i] = xr[i * 64 + lane];
        s += xv[i];
        ss += xv[i] * xv[i];
    }
#pragma unroll
    for (int off = 32; off >= 1; off >>= 1) {
        s += __shfl_xor(s, off);
        ss += __shfl_xor(ss, off);
    }
    float mu = s * (1.0f / ND);
    float var = ss * (1.0f / ND) - mu * mu;
    float r = rsqrtf(fmaxf(var, 0.f) + 1e-5f);
    float le[NE];
#pragma unroll
    for (int e = 0; e < NE; e++) le[e] = 0.f;
#pragma unroll
    for (int i = 0; i < 12; i++) {
        int d = i * 64 + lane;
        float hn = (xv[i] - mu) * r * lg[d] + lb[d];
#pragma unroll
        for (int e = 0; e < NE; e++) le[e] += hn * gw[d * NE + e];
    }
#pragma unroll
    for (int off = 1; off < 64; off <<= 1)
#pragma unroll
        for (int e = 0; e < NE; e++) le[e] += __shfl_xor(le[e], off);
    float sel[NE];
#pragma unroll
    for (int e = 0; e < NE; e++) {
        le[e] += gb[e]; // TAU = 1
        sel[e] = le[e] + be[e];
    }
    int i1 = 0;
#pragma unroll
    for (int e = 1; e < NE; e++) if (sel[e] > sel[i1]) i1 = e;
    int i2 = (i1 == 0) ? 1 : 0;
#pragma unroll
    for (int e = 0; e < NE; e++) if (e != i1 && sel[e] > sel[i2]) i2 = e;
    float l1 = le[i1], l2 = le[i2];
    float m = fmaxf(l1, l2);
    float e1 = __expf(l1 - m), e2 = __expf(l2 - m);
    float inv = 1.0f / (e1 + e2);
    if (lane == 0) {
        gates[t * 2 + 0] = e1 * inv;
        gates[t * 2 + 1] = e2 * inv;
        int p1 = atomicAdd(&cnt[i1], 1);
        if (p1 < NT) list[i1 * NT + p1] = t * 2 + 0;
        int p2 = atomicAdd(&cnt[i2], 1);
        if (p2 < NT) list[i2 * NT + p2] = t * 2 + 1;
    }
}

// ---- MoE GEMM1 (F-pass): mid = gelu(h2_gather @ w1[e][:, fcol0..] + b1) -> bf16 ----
__launch_bounds__(256)
__global__ void moe_gemm1(const bf16* __restrict__ h2, const float* __restrict__ w1,
                          const float* __restrict__ b1, const int* __restrict__ cnt,
                          const int* __restrict__ list, bf16* __restrict__ mid, int fcol0) {
    const int e = blockIdx.x >> 6, tile = blockIdx.x & 63;
    const int n = min(cnt[e], NT);
    const int r0 = tile * 64;
    if (r0 >= n) return;
    const int f0 = blockIdx.y * 64;
    __shared__ int ent[64];
    __shared__ float As[16][65];
    __shared__ float Bs[16][64];
    const int tid = threadIdx.x, tx = tid & 15, ty = tid >> 4;
    if (tid < 64) {
        int en = (r0 + tid < n) ? list[e * NT + r0 + tid] : -1;
        if (en < 0 || en >= 2 * NT) en = -1;
        ent[tid] = en;
    }
    __syncthreads();
    float acc[4][4] = {};
    const float* w1e = w1 + (size_t)e * ND * NF;
    for (int k0 = 0; k0 < ND; k0 += 16) {
#pragma unroll
        for (int i = 0; i < 4; i++) {
            int idx = tid + 256 * i;
            int r = idx >> 4, kk = idx & 15;
            int en = ent[r];
            As[kk][r] = (en >= 0) ? toF(h2[(size_t)(en >> 1) * ND + k0 + kk]) : 0.f;
        }
#pragma unroll
        for (int i = 0; i < 4; i++) {
            int idx = tid + 256 * i;
            int kk = idx >> 6, c = idx & 63;
            Bs[kk][c] = w1e[(size_t)(k0 + kk) * NF + fcol0 + f0 + c];
        }
        __syncthreads();
#pragma unroll
        for (int kk = 0; kk < 16; kk++) {
            float a[4], bb[4];
#pragma unroll
            for (int i = 0; i < 4; i++) a[i] = As[kk][ty + 16 * i];
#pragma unroll
            for (int j = 0; j < 4; j++) bb[j] = Bs[kk][tx + 16 * j];
#pragma unroll
            for (int i = 0; i < 4; i++)
#pragma unroll
                for (int j = 0; j < 4; j++) acc[i][j] += a[i] * bb[j];
        }
        __syncthreads();
    }
#pragma unroll
    for (int i = 0; i < 4; i++) {
        int en = ent[ty + 16 * i];
        if (en < 0) continue;
        int tok = en >> 1, slot = en & 1;
        bf16* mrow = mid + ((size_t)(slot * NT + tok)) * FQ + f0;
#pragma unroll
        for (int j = 0; j < 4; j++) {
            float xvv = acc[i][j] + b1[e * NF + fcol0 + f0 + tx + 16 * j];
            float th = tanhf(0.7978845608028654f * (xvv + 0.044715f * xvv * xvv * xvv));
            mrow[tx + 16 * j] = __float2bfloat16(0.5f * xvv * (1.0f + th));
        }
    }
}

// ---- MoE GEMM2 (F-pass): x1 += gate * (mid_gather @ w2[e][fcol0..] (+b2 pass0)) ----
__launch_bounds__(256)
__global__ void moe_gemm2(const bf16* __restrict__ mid, const float* __restrict__ w2,
                          const float* __restrict__ b2, const int* __restrict__ cnt,
                          const int* __restrict__ list, const float* __restrict__ gates,
                          float* __restrict__ x1, int fcol0, int add_b2) {
    const int e = blockIdx.x >> 6, tile = blockIdx.x & 63;
    const int n = min(cnt[e], NT);
    const int r0 = tile * 64;
    if (r0 >= n) return;
    const int d0 = blockIdx.y * 64;
    __shared__ int ent[64];
    __shared__ float As[16][65];
    __shared__ float Bs[16][64];
    const int tid = threadIdx.x, tx = tid & 15, ty = tid >> 4;
    if (tid < 64) {
        int en = (r0 + tid < n) ? list[e * NT + r0 + tid] : -1;
        if (en < 0 || en >= 2 * NT) en = -1;
        ent[tid] = en;
    }
    __syncthreads();
    float acc[4][4] = {};
    const float* w2e = w2 + (size_t)e * NF * ND;
    for (int k0 = 0; k0 < FQ; k0 += 16) {
#pragma unroll
        for (int i = 0; i < 4; i++) {
            int idx = tid + 256 * i;
            int r = idx >> 4, kk = idx & 15;
            int en = ent[r];
            As[kk][r] = (en >= 0)
                ? toF(mid[((size_t)((en & 1) * NT) + (en >> 1)) * FQ + k0 + kk]) : 0.f;
        }
#pragma unroll
        for (int i = 0; i < 4; i++) {
            int idx = tid + 256 * i;
            int kk = idx >> 6, c = idx & 63;
            Bs[kk][c] = w2e[(size_t)(fcol0 + k0 + kk) * ND + d0 + c];
        }
        __syncthreads();
#pragma unroll
        for (int kk = 0; kk < 16; kk++) {
            float a[4], bb[4];
#pragma unroll
            for (int i = 0; i < 4; i++) a[i] = As[kk][ty + 16 * i];
#pragma unroll
            for (int j = 0; j < 4; j++) bb[j] = Bs[kk][tx + 16 * j];
#pragma unroll
            for (int i = 0; i < 4; i++)
#pragma unroll
                for (int j = 0; j < 4; j++) acc[i][j] += a[i] * bb[j];
        }
        __syncthreads();
    }
#pragma unroll
    for (int i = 0; i < 4; i++) {
        int en = ent[ty + 16 * i];
        if (en < 0) continue;
        int tok = en >> 1;
        float g = gates[en];
#pragma unroll
        for (int j = 0; j < 4; j++) {
            float val = acc[i][j];
            if (add_b2) val += b2[e * ND + d0 + tx + 16 * j];
            atomicAdd(&x1[(size_t)tok * ND + d0 + tx + 16 * j], g * val);
        }
    }
}

// ---------------- Final: out = x1 (fp32 copy) ----------------
__launch_bounds__(256)
__global__ void final_kernel(const float* __restrict__ x1, float* __restrict__ out) {
    int i = blockIdx.x * 256 + threadIdx.x;
    out[i] = x1[i];
}

extern "C" void kernel_launch(void* const* d_in, const int* in_sizes, int n_in,
                              void* d_out, int out_size, void* d_ws, size_t ws_size,
                              hipStream_t stream) {
    const float* x    = (const float*)d_in[0];
    const float* wq   = (const float*)d_in[1];
    const float* wk   = (const float*)d_in[2];
    const float* wv   = (const float*)d_in[3];
    const float* wo   = (const float*)d_in[4];
    const float* ln1g = (const float*)d_in[5];
    const float* ln1b = (const float*)d_in[6];
    const float* ln2g = (const float*)d_in[7];
    const float* ln2b = (const float*)d_in[8];
    const float* gw   = (const float*)d_in[9];
    const float* gb   = (const float*)d_in[10];
    const float* be   = (const float*)d_in[11];
    const float* w1   = (const float*)d_in[12];
    const float* b1   = (const float*)d_in[13];
    const float* w2   = (const float*)d_in[14];
    const float* b2   = (const float*)d_in[15];
    float* out = (float*)d_out;

    const size_t TDn = (size_t)NT * ND; // 3,145,728
    const size_t TGn = (size_t)NT * GW; // 1,048,576
    float* W = (float*)d_ws;
    // Workspace 40.2 MiB:
    // [routing 41216 f][x1 fp32 TDn][h fp32 TDn][R: q,k,v,og fp32 4*TGn]
    // h2 (bf16, TDn) reuses h's region; mid (bf16, 2*NT*FQ = 2*TDn) reuses R.
    int*   cnt   = (int*)W;                  // 8
    int*   list  = cnt + NE;                 // 32768
    float* gates = (float*)(list + NE * NT); // 8192 (ends 40968)
    float* x1 = W + 41216;
    float* h  = x1 + TDn;
    float* R0 = h + TDn;
    float* q  = R0;
    float* k  = R0 + TGn;
    float* v  = R0 + 2 * TGn;
    float* og = R0 + 3 * TGn;
    bf16*  h2  = (bf16*)h;   // LN2 out (bf16), overwrites LN1 h after attention
    bf16*  mid = (bf16*)R0;  // [2*NT][FQ] bf16 = 2*TDn bf16, fits in 4*TGn floats

    hipMemsetAsync(cnt, 0, NE * sizeof(int), stream);

    ln_kernel<float><<<NT, 256, 0, stream>>>(x, ln1g, ln1b, h);
    for (int g = 0; g < NG; g++) {
        dim3 gq(NT / 64, GW / 64);
        gemm_kernel<0><<<gq, 256, 0, stream>>>(h, ND, wq, ND, g * GW, nullptr, q, GW, ND);
        gemm_kernel<0><<<gq, 256, 0, stream>>>(h, ND, wk, ND, g * GW, nullptr, k, GW, ND);
        gemm_kernel<0><<<gq, 256, 0, stream>>>(h, ND, wv, ND, g * GW, nullptr, v, GW, ND);
        attn_kernel<<<dim3(NS / 64, HG, NB), 256, 0, stream>>>(q, k, v, og);
        // x1 (g==0: = x + og@wo_g ; else += og@wo_g). wo rows g*GW..(g+1)*GW.
        if (g == 0)
            gemm_kernel<1><<<dim3(NT / 64, ND / 64), 256, 0, stream>>>(
                og, GW, wo + (size_t)g * GW * ND, ND, 0, x, x1, ND, GW);
        else
            gemm_kernel<2><<<dim3(NT / 64, ND / 64), 256, 0, stream>>>(
                og, GW, wo + (size_t)g * GW * ND, ND, 0, nullptr, x1, ND, GW);
    }
    route_kernel<<<NT / 4, 256, 0, stream>>>(x1, ln2g, ln2b, gw, gb, be, cnt, list, gates);
    ln_kernel<bf16><<<NT, 256, 0, stream>>>(x1, ln2g, ln2b, h2);
    for (int p = 0; p < NP; p++) {
        int fcol0 = p * FQ;
        moe_gemm1<<<dim3(NE * (NT / 64), FQ / 64), 256, 0, stream>>>(
            h2, w1, b1, cnt, list, mid, fcol0);
        moe_gemm2<<<dim3(NE * (NT / 64), ND / 64), 256, 0, stream>>>(
            mid, w2, b2, cnt, list, gates, x1, fcol0, p == 0 ? 1 : 0);
    }
    final_kernel<<<TDn / 256, 256, 0, stream>>>(x1, out);
}

// Round 6
// 1826.872 us; speedup vs baseline: 2.2741x; 2.2741x over previous
//
#include <hip/hip_runtime.h>
#include <hip/hip_bf16.h>

using bf16 = __hip_bfloat16;

constexpr int NB = 8, NS = 512, ND = 768, NH = 12, NE = 8, NF = 3072, NT = 4096;
constexpr int HG = 4;            // heads per attention group
constexpr int NG = NH / HG;      // 3 groups
constexpr int GW = HG * 64;      // 256: qkv group width
constexpr int FQ = 768;          // F columns per MoE pass
constexpr int NP = NF / FQ;      // 4 passes

typedef __attribute__((ext_vector_type(8))) short v8s;
typedef __attribute__((ext_vector_type(4))) float v4f;

__device__ __forceinline__ float toF(float v) { return v; }
__device__ __forceinline__ float toF(bf16 v) { return __bfloat162float(v); }
__device__ __forceinline__ short f2bf(float v) {
    bf16 t = __float2bfloat16(v);
    return *reinterpret_cast<short*>(&t);
}
__device__ __forceinline__ float bf2f(short s) {
    bf16 t = *reinterpret_cast<bf16*>(&s);
    return __bfloat162float(t);
}

// ---------------- LayerNorm (fp32 in) -> TOUT out ----------------
template <typename TOUT>
__launch_bounds__(256)
__global__ void ln_kernel(const float* __restrict__ x, const float* __restrict__ g,
                          const float* __restrict__ b, TOUT* __restrict__ out) {
    const int t = blockIdx.x;
    const int tid = threadIdx.x;
    const float* xr = x + (size_t)t * ND;
    float v0 = xr[tid], v1 = xr[tid + 256], v2 = xr[tid + 512];
    float s = v0 + v1 + v2;
    float ss = v0 * v0 + v1 * v1 + v2 * v2;
#pragma unroll
    for (int off = 32; off >= 1; off >>= 1) {
        s += __shfl_xor(s, off);
        ss += __shfl_xor(ss, off);
    }
    __shared__ float rs[4], rss[4];
    const int wv = tid >> 6, ln = tid & 63;
    if (ln == 0) { rs[wv] = s; rss[wv] = ss; }
    __syncthreads();
    float S = rs[0] + rs[1] + rs[2] + rs[3];
    float SS = rss[0] + rss[1] + rss[2] + rss[3];
    float mu = S * (1.0f / ND);
    float var = SS * (1.0f / ND) - mu * mu;
    float r = rsqrtf(fmaxf(var, 0.f) + 1e-5f);
    TOUT* orow = out + (size_t)t * ND;
    float o0 = (v0 - mu) * r * g[tid]       + b[tid];
    float o1 = (v1 - mu) * r * g[tid + 256] + b[tid + 256];
    float o2 = (v2 - mu) * r * g[tid + 512] + b[tid + 512];
    if constexpr (sizeof(TOUT) == 2) {
        orow[tid] = __float2bfloat16(o0);
        orow[tid + 256] = __float2bfloat16(o1);
        orow[tid + 512] = __float2bfloat16(o2);
    } else {
        orow[tid] = o0; orow[tid + 256] = o1; orow[tid + 512] = o2;
    }
}

// ---- fp32 GEMM: 64x64 tile, BK=16, thread owns contiguous 4x4 (b128 LDS reads).
//      RES_MODE: 0 store, 1 store Res+acc, 2 C += acc ----
template <int RES_MODE>
__launch_bounds__(256)
__global__ void gemm_kernel(const float* __restrict__ A, int lda, const float* __restrict__ Bw,
                            int ldb, int bcol0, const float* __restrict__ Res,
                            float* __restrict__ C, int ldc, int Kd) {
    __shared__ float As[16][68]; // stride 68 floats = 272B (16B-aligned rows for b128)
    __shared__ float Bs[16][64];
    const int m0 = blockIdx.x * 64, n0 = blockIdx.y * 64;
    const int tid = threadIdx.x, tx = tid & 15, ty = tid >> 4;
    float acc[4][4] = {};
    for (int k0 = 0; k0 < Kd; k0 += 16) {
#pragma unroll
        for (int i = 0; i < 4; i++) {
            int idx = tid + 256 * i;
            int r = idx >> 4, kk = idx & 15;
            As[kk][r] = A[(size_t)(m0 + r) * lda + k0 + kk];
        }
#pragma unroll
        for (int i = 0; i < 4; i++) {
            int idx = tid + 256 * i;
            int kk = idx >> 6, c = idx & 63;
            Bs[kk][c] = Bw[(size_t)(k0 + kk) * ldb + bcol0 + n0 + c];
        }
        __syncthreads();
#pragma unroll
        for (int kk = 0; kk < 16; kk++) {
            v4f a = *(const v4f*)&As[kk][ty * 4];
            v4f bb = *(const v4f*)&Bs[kk][tx * 4];
#pragma unroll
            for (int i = 0; i < 4; i++)
#pragma unroll
                for (int j = 0; j < 4; j++) acc[i][j] += a[i] * bb[j];
        }
        __syncthreads();
    }
#pragma unroll
    for (int i = 0; i < 4; i++) {
        int r = m0 + ty * 4 + i;
#pragma unroll
        for (int j = 0; j < 4; j++) {
            int c = n0 + tx * 4 + j;
            size_t ci = (size_t)r * ldc + c;
            if (RES_MODE == 0) C[ci] = acc[i][j];
            else if (RES_MODE == 1) C[ci] = Res[ci] + acc[i][j];
            else C[ci] += acc[i][j];
        }
    }
}

// ------- fp32 flash attention (one head of a group); q/k/v/o [NT, GW] -------
__launch_bounds__(256)
__global__ void attn_kernel(const float* __restrict__ q, const float* __restrict__ k,
                            const float* __restrict__ v, float* __restrict__ o) {
    __shared__ float qs[64][65];
    __shared__ float kp[64][65]; // K tile, reused as P tile
    __shared__ float vs[64][65];
    const int qt = blockIdx.x, hl = blockIdx.y, b = blockIdx.z;
    const int tid = threadIdx.x, tx = tid & 15, ty = tid >> 4;
    const int hc = hl * 64;
#pragma unroll
    for (int i = 0; i < 16; i++) {
        int idx = tid + 256 * i;
        int r = idx >> 6, c = idx & 63;
        qs[r][c] = q[((size_t)b * NS + qt * 64 + r) * GW + hc + c];
    }
    float oa[4][4] = {};
    float mi[4], li[4], al[4];
#pragma unroll
    for (int i = 0; i < 4; i++) { mi[i] = -1.0e30f; li[i] = 0.f; }
    for (int kt = 0; kt < NS / 64; kt++) {
        __syncthreads();
#pragma unroll
        for (int i = 0; i < 16; i++) {
            int idx = tid + 256 * i;
            int r = idx >> 6, c = idx & 63;
            size_t ga = ((size_t)b * NS + kt * 64 + r) * GW + hc + c;
            kp[r][c] = k[ga];
            vs[r][c] = v[ga];
        }
        __syncthreads();
        float s[4][4] = {};
#pragma unroll
        for (int d = 0; d < 64; d++) {
            float a[4], bb[4];
#pragma unroll
            for (int i = 0; i < 4; i++) a[i] = qs[ty + 16 * i][d];
#pragma unroll
            for (int j = 0; j < 4; j++) bb[j] = kp[tx + 16 * j][d];
#pragma unroll
            for (int i = 0; i < 4; i++)
#pragma unroll
                for (int j = 0; j < 4; j++) s[i][j] += a[i] * bb[j];
        }
#pragma unroll
        for (int i = 0; i < 4; i++) {
#pragma unroll
            for (int j = 0; j < 4; j++) s[i][j] *= 0.125f; // 1/sqrt(DH=64)
            float mt = fmaxf(fmaxf(s[i][0], s[i][1]), fmaxf(s[i][2], s[i][3]));
#pragma unroll
            for (int off = 1; off < 16; off <<= 1) mt = fmaxf(mt, __shfl_xor(mt, off));
            float mn = fmaxf(mi[i], mt);
            al[i] = __expf(mi[i] - mn);
            mi[i] = mn;
            float rsum = 0.f;
#pragma unroll
            for (int j = 0; j < 4; j++) {
                s[i][j] = __expf(s[i][j] - mn);
                rsum += s[i][j];
            }
#pragma unroll
            for (int off = 1; off < 16; off <<= 1) rsum += __shfl_xor(rsum, off);
            li[i] = li[i] * al[i] + rsum;
        }
        __syncthreads(); // reads of kp-as-K done
#pragma unroll
        for (int i = 0; i < 4; i++)
#pragma unroll
            for (int j = 0; j < 4; j++) {
                kp[ty + 16 * i][tx + 16 * j] = s[i][j];
                oa[i][j] *= al[i];
            }
        __syncthreads(); // P visible
#pragma unroll
        for (int d = 0; d < 64; d++) {
            float a[4], bb[4];
#pragma unroll
            for (int i = 0; i < 4; i++) a[i] = kp[ty + 16 * i][d];
#pragma unroll
            for (int j = 0; j < 4; j++) bb[j] = vs[d][tx + 16 * j];
#pragma unroll
            for (int i = 0; i < 4; i++)
#pragma unroll
                for (int j = 0; j < 4; j++) oa[i][j] += a[i] * bb[j];
        }
    }
#pragma unroll
    for (int i = 0; i < 4; i++) {
        float inv = 1.0f / li[i];
#pragma unroll
        for (int j = 0; j < 4; j++)
            o[((size_t)b * NS + qt * 64 + ty + 16 * i) * GW + hc + tx + 16 * j] = oa[i][j] * inv;
    }
}

// ------- Routing: inline fp32 LN2(x1) -> logits -> top-2. One wave per token. -------
__launch_bounds__(256)
__global__ void route_kernel(const float* __restrict__ x1, const float* __restrict__ lg,
                             const float* __restrict__ lb, const float* __restrict__ gw,
                             const float* __restrict__ gb, const float* __restrict__ be,
                             int* __restrict__ cnt, int* __restrict__ list,
                             float* __restrict__ gates) {
    const int lane = threadIdx.x & 63;
    const int t = blockIdx.x * 4 + (threadIdx.x >> 6);
    if (t >= NT) return;
    const float* xr = x1 + (size_t)t * ND;
    float xv[12];
    float s = 0.f, ss = 0.f;
#pragma unroll
    for (int i = 0; i < 12; i++) {
        xv[i] = xr[i * 64 + lane];
        s += xv[i];
        ss += xv[i] * xv[i];
    }
#pragma unroll
    for (int off = 32; off >= 1; off >>= 1) {
        s += __shfl_xor(s, off);
        ss += __shfl_xor(ss, off);
    }
    float mu = s * (1.0f / ND);
    float var = ss * (1.0f / ND) - mu * mu;
    float r = rsqrtf(fmaxf(var, 0.f) + 1e-5f);
    float le[NE];
#pragma unroll
    for (int e = 0; e < NE; e++) le[e] = 0.f;
#pragma unroll
    for (int i = 0; i < 12; i++) {
        int d = i * 64 + lane;
        float hn = (xv[i] - mu) * r * lg[d] + lb[d];
#pragma unroll
        for (int e = 0; e < NE; e++) le[e] += hn * gw[d * NE + e];
    }
#pragma unroll
    for (int off = 1; off < 64; off <<= 1)
#pragma unroll
        for (int e = 0; e < NE; e++) le[e] += __shfl_xor(le[e], off);
    float sel[NE];
#pragma unroll
    for (int e = 0; e < NE; e++) {
        le[e] += gb[e]; // TAU = 1
        sel[e] = le[e] + be[e];
    }
    int i1 = 0;
#pragma unroll
    for (int e = 1; e < NE; e++) if (sel[e] > sel[i1]) i1 = e;
    int i2 = (i1 == 0) ? 1 : 0;
#pragma unroll
    for (int e = 0; e < NE; e++) if (e != i1 && sel[e] > sel[i2]) i2 = e;
    float l1 = le[i1], l2 = le[i2];
    float m = fmaxf(l1, l2);
    float e1 = __expf(l1 - m), e2 = __expf(l2 - m);
    float inv = 1.0f / (e1 + e2);
    if (lane == 0) {
        gates[t * 2 + 0] = e1 * inv;
        gates[t * 2 + 1] = e2 * inv;
        int p1 = atomicAdd(&cnt[i1], 1);
        if (p1 < NT) list[i1 * NT + p1] = t * 2 + 0;
        int p2 = atomicAdd(&cnt[i2], 1);
        if (p2 < NT) list[i2 * NT + p2] = t * 2 + 1;
    }
}

// ==================== MFMA MoE GEMMs ====================
// 64x64 tile, BK=32, 4 waves x 4 x mfma_f32_16x16x32_bf16.
// A: gathered bf16 rows staged [64][40] (row-major, 16B-aligned b128 frags).
// B: fp32 weights converted in staging, stored transposed [n][k] [64][40].
// Frag layouts (verified m89/m120): A[m=lane&15][k=quad*8+j],
// B[k=quad*8+j][n=lane&15], C/D row=quad*4+reg, col=lane&15.

// ---- MoE GEMM1 (F-pass): mid = gelu(h2_gather @ w1[e][:, fcol0..] + b1) -> bf16 ----
__launch_bounds__(256)
__global__ void moe_gemm1(const bf16* __restrict__ h2, const float* __restrict__ w1,
                          const float* __restrict__ b1, const int* __restrict__ cnt,
                          const int* __restrict__ list, bf16* __restrict__ mid, int fcol0) {
    const int e = blockIdx.x >> 6, tile = blockIdx.x & 63;
    const int n = min(cnt[e], NT);
    const int r0 = tile * 64;
    if (r0 >= n) return;
    const int f0 = blockIdx.y * 64;
    __shared__ int ent[64];
    __shared__ short As[64 * 40];
    __shared__ short Bs[64 * 40];
    const int tid = threadIdx.x;
    const int lane = tid & 63, wv = tid >> 6;
    const int qd = lane >> 4, l16 = lane & 15;
    if (tid < 64) {
        int en = (r0 + tid < n) ? list[e * NT + r0 + tid] : -1;
        if (en < 0 || en >= 2 * NT) en = -1;
        ent[tid] = en;
    }
    __syncthreads();
    v4f acc[4] = {};
    const float* w1e = w1 + (size_t)e * ND * NF + fcol0 + f0;
    const int ar = tid >> 2, ac = (tid & 3) * 8;       // A staging: row, k-offset
    const int bn = tid & 63, bk = (tid >> 6) * 8;      // B staging: n, k-offset
    const int aen = ent[ar];
    for (int k0 = 0; k0 < ND; k0 += 32) {
        v8s av = {};
        if (aen >= 0)
            av = *(const v8s*)((const short*)h2 + (size_t)(aen >> 1) * ND + k0 + ac);
        *(v8s*)&As[ar * 40 + ac] = av;
        {
            const float* src = w1e + (size_t)(k0 + bk) * NF + bn;
            v8s bv;
#pragma unroll
            for (int j = 0; j < 8; j++) bv[j] = f2bf(src[(size_t)j * NF]);
            *(v8s*)&Bs[bn * 40 + bk] = bv;
        }
        __syncthreads();
        v8s bfrag = *(const v8s*)&Bs[(wv * 16 + l16) * 40 + qd * 8];
#pragma unroll
        for (int t = 0; t < 4; t++) {
            v8s afrag = *(const v8s*)&As[(t * 16 + l16) * 40 + qd * 8];
            acc[t] = __builtin_amdgcn_mfma_f32_16x16x32_bf16(afrag, bfrag, acc[t], 0, 0, 0);
        }
        __syncthreads();
    }
    const int col = wv * 16 + l16;
    const float bias = b1[e * NF + fcol0 + f0 + col];
#pragma unroll
    for (int t = 0; t < 4; t++) {
#pragma unroll
        for (int rg = 0; rg < 4; rg++) {
            int en = ent[t * 16 + qd * 4 + rg];
            if (en < 0) continue;
            float xv = acc[t][rg] + bias;
            float th = tanhf(0.7978845608028654f * (xv + 0.044715f * xv * xv * xv));
            mid[((size_t)((en & 1) * NT) + (en >> 1)) * FQ + f0 + col] =
                __float2bfloat16(0.5f * xv * (1.0f + th));
        }
    }
}

// ---- MoE GEMM2 (F-pass): x1 += gate * (mid_gather @ w2[e][fcol0..] (+b2 pass0)) ----
__launch_bounds__(256)
__global__ void moe_gemm2(const bf16* __restrict__ mid, const float* __restrict__ w2,
                          const float* __restrict__ b2, const int* __restrict__ cnt,
                          const int* __restrict__ list, const float* __restrict__ gates,
                          float* __restrict__ x1, int fcol0, int add_b2) {
    const int e = blockIdx.x >> 6, tile = blockIdx.x & 63;
    const int n = min(cnt[e], NT);
    const int r0 = tile * 64;
    if (r0 >= n) return;
    const int d0 = blockIdx.y * 64;
    __shared__ int ent[64];
    __shared__ short As[64 * 40];
    __shared__ short Bs[64 * 40];
    const int tid = threadIdx.x;
    const int lane = tid & 63, wv = tid >> 6;
    const int qd = lane >> 4, l16 = lane & 15;
    if (tid < 64) {
        int en = (r0 + tid < n) ? list[e * NT + r0 + tid] : -1;
        if (en < 0 || en >= 2 * NT) en = -1;
        ent[tid] = en;
    }
    __syncthreads();
    v4f acc[4] = {};
    const float* w2e = w2 + (size_t)e * NF * ND + d0;
    const int ar = tid >> 2, ac = (tid & 3) * 8;
    const int bn = tid & 63, bk = (tid >> 6) * 8;
    const int aen = ent[ar];
    for (int k0 = 0; k0 < FQ; k0 += 32) {
        v8s av = {};
        if (aen >= 0)
            av = *(const v8s*)((const short*)mid +
                               ((size_t)((aen & 1) * NT) + (aen >> 1)) * FQ + k0 + ac);
        *(v8s*)&As[ar * 40 + ac] = av;
        {
            const float* src = w2e + (size_t)(fcol0 + k0 + bk) * ND + bn;
            v8s bv;
#pragma unroll
            for (int j = 0; j < 8; j++) bv[j] = f2bf(src[(size_t)j * ND]);
            *(v8s*)&Bs[bn * 40 + bk] = bv;
        }
        __syncthreads();
        v8s bfrag = *(const v8s*)&Bs[(wv * 16 + l16) * 40 + qd * 8];
#pragma unroll
        for (int t = 0; t < 4; t++) {
            v8s afrag = *(const v8s*)&As[(t * 16 + l16) * 40 + qd * 8];
            acc[t] = __builtin_amdgcn_mfma_f32_16x16x32_bf16(afrag, bfrag, acc[t], 0, 0, 0);
        }
        __syncthreads();
    }
    const int col = wv * 16 + l16;
    const float bias = add_b2 ? b2[e * ND + d0 + col] : 0.f;
#pragma unroll
    for (int t = 0; t < 4; t++) {
#pragma unroll
        for (int rg = 0; rg < 4; rg++) {
            int en = ent[t * 16 + qd * 4 + rg];
            if (en < 0) continue;
            float g = gates[en];
            atomicAdd(&x1[(size_t)(en >> 1) * ND + d0 + col], g * (acc[t][rg] + bias));
        }
    }
}

// ---------------- Final: out = x1 (fp32 copy) ----------------
__launch_bounds__(256)
__global__ void final_kernel(const float* __restrict__ x1, float* __restrict__ out) {
    int i = blockIdx.x * 256 + threadIdx.x;
    out[i] = x1[i];
}

extern "C" void kernel_launch(void* const* d_in, const int* in_sizes, int n_in,
                              void* d_out, int out_size, void* d_ws, size_t ws_size,
                              hipStream_t stream) {
    const float* x    = (const float*)d_in[0];
    const float* wq   = (const float*)d_in[1];
    const float* wk   = (const float*)d_in[2];
    const float* wv   = (const float*)d_in[3];
    const float* wo   = (const float*)d_in[4];
    const float* ln1g = (const float*)d_in[5];
    const float* ln1b = (const float*)d_in[6];
    const float* ln2g = (const float*)d_in[7];
    const float* ln2b = (const float*)d_in[8];
    const float* gw   = (const float*)d_in[9];
    const float* gb   = (const float*)d_in[10];
    const float* be   = (const float*)d_in[11];
    const float* w1   = (const float*)d_in[12];
    const float* b1   = (const float*)d_in[13];
    const float* w2   = (const float*)d_in[14];
    const float* b2   = (const float*)d_in[15];
    float* out = (float*)d_out;

    const size_t TDn = (size_t)NT * ND; // 3,145,728
    const size_t TGn = (size_t)NT * GW; // 1,048,576
    float* W = (float*)d_ws;
    // Workspace 40.2 MiB:
    // [routing 41216 f][x1 fp32 TDn][h fp32 TDn][R: q,k,v,og fp32 4*TGn]
    // h2 (bf16, TDn) reuses h's region; mid (bf16, 2*NT*FQ = 2*TDn) reuses R.
    int*   cnt   = (int*)W;                  // 8
    int*   list  = cnt + NE;                 // 32768
    float* gates = (float*)(list + NE * NT); // 8192 (ends 40968)
    float* x1 = W + 41216;
    float* h  = x1 + TDn;
    float* R0 = h + TDn;
    float* q  = R0;
    float* k  = R0 + TGn;
    float* v  = R0 + 2 * TGn;
    float* og = R0 + 3 * TGn;
    bf16*  h2  = (bf16*)h;   // LN2 out (bf16), overwrites LN1 h after attention
    bf16*  mid = (bf16*)R0;  // [2*NT][FQ] bf16 = 2*TDn bf16, fits in 4*TGn floats

    hipMemsetAsync(cnt, 0, NE * sizeof(int), stream);

    ln_kernel<float><<<NT, 256, 0, stream>>>(x, ln1g, ln1b, h);
    for (int g = 0; g < NG; g++) {
        dim3 gq(NT / 64, GW / 64);
        gemm_kernel<0><<<gq, 256, 0, stream>>>(h, ND, wq, ND, g * GW, nullptr, q, GW, ND);
        gemm_kernel<0><<<gq, 256, 0, stream>>>(h, ND, wk, ND, g * GW, nullptr, k, GW, ND);
        gemm_kernel<0><<<gq, 256, 0, stream>>>(h, ND, wv, ND, g * GW, nullptr, v, GW, ND);
        attn_kernel<<<dim3(NS / 64, HG, NB), 256, 0, stream>>>(q, k, v, og);
        // x1 (g==0: = x + og@wo_g ; else += og@wo_g). wo rows g*GW..(g+1)*GW.
        if (g == 0)
            gemm_kernel<1><<<dim3(NT / 64, ND / 64), 256, 0, stream>>>(
                og, GW, wo + (size_t)g * GW * ND, ND, 0, x, x1, ND, GW);
        else
            gemm_kernel<2><<<dim3(NT / 64, ND / 64), 256, 0, stream>>>(
                og, GW, wo + (size_t)g * GW * ND, ND, 0, nullptr, x1, ND, GW);
    }
    route_kernel<<<NT / 4, 256, 0, stream>>>(x1, ln2g, ln2b, gw, gb, be, cnt, list, gates);
    ln_kernel<bf16><<<NT, 256, 0, stream>>>(x1, ln2g, ln2b, h2);
    for (int p = 0; p < NP; p++) {
        int fcol0 = p * FQ;
        moe_gemm1<<<dim3(NE * (NT / 64), FQ / 64), 256, 0, stream>>>(
            h2, w1, b1, cnt, list, mid, fcol0);
        moe_gemm2<<<dim3(NE * (NT / 64), ND / 64), 256, 0, stream>>>(
            mid, w2, b2, cnt, list, gates, x1, fcol0, p == 0 ? 1 : 0);
    }
    final_kernel<<<TDn / 256, 256, 0, stream>>>(x1, out);
}